// Round 2
// baseline (4120.982 us; speedup 1.0000x reference)
//
#include <hip/hip_runtime.h>
#include <stdint.h>

#define NS 64      // samples
#define NA 256     // assets
#define NC 8       // clusters
#define NI 10      // inits
#define MAXIT 30   // lloyd iterations

typedef unsigned int u32;

struct Key { u32 x, y; };

// Threefry-2x32, 20 rounds — exact JAX semantics.
__device__ __forceinline__ void tf2x32(u32 k0, u32 k1, u32 c0, u32 c1, u32& o0, u32& o1) {
  u32 ks0 = k0, ks1 = k1, ks2 = k0 ^ k1 ^ 0x1BD11BDAu;
  u32 x0 = c0 + ks0, x1 = c1 + ks1;
#define TFR(r) { x0 += x1; x1 = (x1 << (r)) | (x1 >> (32 - (r))); x1 ^= x0; }
  TFR(13) TFR(15) TFR(26) TFR(6)
  x0 += ks1; x1 += ks2 + 1u;
  TFR(17) TFR(29) TFR(16) TFR(24)
  x0 += ks2; x1 += ks0 + 2u;
  TFR(13) TFR(15) TFR(26) TFR(6)
  x0 += ks0; x1 += ks1 + 3u;
  TFR(17) TFR(29) TFR(16) TFR(24)
  x0 += ks1; x1 += ks2 + 4u;
  TFR(13) TFR(15) TFR(26) TFR(6)
  x0 += ks2; x1 += ks0 + 5u;
#undef TFR
  o0 = x0; o1 = x1;
}

// jax_threefry_partitionable=True (default in modern JAX) semantics:
// split(key, n)[j]           = threefry2x32(key, hi=0, lo=j)  -> (o0, o1) is the new key
// random_bits(key, 32, (n,))[i] = o0 ^ o1 of threefry2x32(key, 0, i)
__device__ __forceinline__ Key key_row(Key k, u32 j) {
  Key r; tf2x32(k.x, k.y, 0u, j, r.x, r.y); return r;
}
__device__ __forceinline__ u32 rbits32(Key k, u32 i) {
  u32 o0, o1; tf2x32(k.x, k.y, 0u, i, o0, o1); return o0 ^ o1;
}

// ---------------- corr (f64) ----------------
__global__ void nco_corr_kernel(const float* __restrict__ cov, double* __restrict__ corr) {
  int b = blockIdx.x;            // b = j*256 + i
  int j = b >> 8, i = b & 255, d = threadIdx.x;
  const float* C = cov + (size_t)j * NA * NA;
  double di = sqrt((double)C[i * NA + i]);
  double dd = sqrt((double)C[d * NA + d]);
  corr[(size_t)b * NA + d] = (double)C[i * NA + d] / (di * dd);
}

// ---------------- init indices (JAX PRNG chain, partitionable threefry) ----------------
__global__ void nco_init_kernel(int* __restrict__ initIdx) {
  int blk = blockIdx.x;          // j*NI + m
  int j = blk / NI, m = blk % NI;
  int t = threadIdx.x;
  __shared__ u32 bits[NA];

  Key base; base.x = 0u; base.y = 42u;          // jax.random.key(42) -> [0, 42]
  Key skey = key_row(base, (u32)j);             // split(base, 64)[j]
  Key ikey = key_row(skey, (u32)m);             // split(skey, 10)[m]
  Key sub  = key_row(ikey, 1u);                 // _shuffle: key,use_key = split(ikey); use_key = row 1
  bits[t] = rbits32(sub, (u32)t);               // random_bits(use_key, 32, (256,))
  __syncthreads();

  // stable rank: smaller bits first, ties -> smaller index (lax.sort_key_val is stable)
  u32 mine = bits[t];
  int rank = 0;
  for (int u = 0; u < NA; u++) {
    u32 b2 = bits[u];
    rank += (b2 < mine) || (b2 == mine && u < t);
  }
  if (rank < NC) initIdx[blk * NC + rank] = t;
}

// ---------------- k-means (Lloyd, f64) ----------------
__global__ __launch_bounds__(256) void nco_kmeans_kernel(
    const double* __restrict__ corr, const int* __restrict__ initIdx,
    int* __restrict__ ixsAll, double* __restrict__ inertiaAll) {
  int blk = blockIdx.x;          // j*NI + m
  int j = blk / NI;
  int t = threadIdx.x;
  const double* X = corr + (size_t)j * NA * NA;

  __shared__ double cent[NC][NA];
  __shared__ int    ixs[NA];
  __shared__ double cnts[NC];
  __shared__ double mind[NA];

  for (int c = 0; c < NC; c++) {
    int p = initIdx[blk * NC + c];
    cent[c][t] = X[(size_t)p * NA + t];
  }
  __syncthreads();

  int myix = 0;
  for (int it = 0; it <= MAXIT; it++) {
    // distances of point t to 8 centers
    double acc[NC];
#pragma unroll
    for (int c = 0; c < NC; c++) acc[c] = 0.0;
    for (int d = 0; d < NA; d++) {
      double x = X[(size_t)t * NA + d];
#pragma unroll
      for (int c = 0; c < NC; c++) { double df = x - cent[c][d]; acc[c] = fma(df, df, acc[c]); }
    }
    double best = acc[0]; int bi = 0;
#pragma unroll
    for (int c = 1; c < NC; c++) if (acc[c] < best) { best = acc[c]; bi = c; }  // first-min = jnp.argmin
    ixs[t] = bi; mind[t] = best; myix = bi;
    __syncthreads();
    if (it == MAXIT) break;

    if (t < NC) {
      double cnt = 0.0;
      for (int i = 0; i < NA; i++) cnt += (ixs[i] == t) ? 1.0 : 0.0;
      cnts[t] = cnt;
    }
    __syncthreads();

    // new centers: thread t owns dimension t for all clusters (fixed i-order sums)
    double s[NC];
#pragma unroll
    for (int c = 0; c < NC; c++) s[c] = 0.0;
    for (int i = 0; i < NA; i++) {
      double x = X[(size_t)i * NA + t];
      int ic = ixs[i];
#pragma unroll
      for (int c = 0; c < NC; c++) s[c] += (ic == c) ? x : 0.0;
    }
#pragma unroll
    for (int c = 0; c < NC; c++) {
      double cnt = cnts[c];
      cent[c][t] = (cnt > 0.0) ? (s[c] / fmax(cnt, 1.0)) : cent[c][t];
    }
    __syncthreads();
  }

  ixsAll[blk * NA + t] = myix;
  if (t == 0) {
    double ssum = 0.0;
    for (int i = 0; i < NA; i++) ssum += mind[i];
    inertiaAll[blk] = ssum;
  }
}

// ---------------- per-sample solves + inter-cluster + output ----------------
__global__ __launch_bounds__(256) void nco_solve_kernel(
    const float* __restrict__ cov, const float* __restrict__ rets,
    const int* __restrict__ ixsAll, const double* __restrict__ inertiaAll,
    double* __restrict__ buf_all, float* __restrict__ out) {
  int j = blockIdx.x, t = threadIdx.x;
  const float* C = cov + (size_t)j * NA * NA;
  const float* r = rets + (size_t)j * NA;
  double* buf = buf_all + (size_t)j * NA * NA;   // packed m x m submatrix (f64)

  __shared__ int    sbest;
  __shared__ int    li[NA];
  __shared__ int    smm;
  __shared__ double rhs[NA];
  __shared__ double wsub[NA];
  __shared__ double sdenom;
  __shared__ double wc[NC][NA];     // w_cols (k, n)
  __shared__ double tmpL[NC][NA];   // w^T @ cov
  __shared__ double interA[NC][NC];
  __shared__ double interb[NC];
  __shared__ double wi[NC];

  if (t == 0) {
    double bv = inertiaAll[j * NI]; int b = 0;
    for (int m = 1; m < NI; m++) {
      double v = inertiaAll[j * NI + m];
      if (v < bv) { bv = v; b = m; }               // first-min
    }
    sbest = b;
  }
  __syncthreads();
  const int* ixs = ixsAll + (size_t)(j * NI + sbest) * NA;

  for (int c = 0; c < NC; c++) {
    if (t == 0) {
      int m = 0;
      for (int i = 0; i < NA; i++) if (ixs[i] == c) li[m++] = i;
      smm = m;
    }
    wc[c][t] = 0.0;
    __syncthreads();
    int m = smm;
    if (m > 0) {
      if (t < m) {
        int ra = li[t];
        const float* Crow = C + (size_t)ra * NA;
        for (int b2 = 0; b2 < m; b2++) buf[(size_t)t * m + b2] = (double)Crow[li[b2]];
        rhs[t] = (double)r[ra];
      }
      __syncthreads();
      // Gaussian elimination (SPD submatrix -> no pivoting needed)
      for (int k = 0; k < m - 1; k++) {
        double piv = buf[(size_t)k * m + k];
        if (t > k && t < m) {
          double f = buf[(size_t)t * m + k] / piv;
          rhs[t] -= f * rhs[k];
          for (int b2 = k + 1; b2 < m; b2++)
            buf[(size_t)t * m + b2] -= f * buf[(size_t)k * m + b2];
        }
        __syncthreads();
      }
      // back substitution (column-oriented, parallel)
      for (int a = m - 1; a >= 0; a--) {
        if (t == a) wsub[a] = rhs[a] / buf[(size_t)a * m + a];
        __syncthreads();
        if (t < a) rhs[t] -= buf[(size_t)t * m + a] * wsub[a];
        __syncthreads();
      }
      if (t == 0) {
        double s = 0.0;
        for (int a = 0; a < m; a++) s += wsub[a];
        sdenom = s;
      }
      __syncthreads();
      if (t < m) wc[c][li[t]] = (sdenom != 0.0) ? (wsub[t] / sdenom) : 0.0;
    }
    __syncthreads();
  }

  // tmpL[c][q] = sum_p wc[c][p] * cov[p][q]  (thread t owns column q=t)
  {
    double tcol[NC];
#pragma unroll
    for (int c = 0; c < NC; c++) tcol[c] = 0.0;
    for (int p = 0; p < NA; p++) {
      double cv = (double)C[(size_t)p * NA + t];
#pragma unroll
      for (int c = 0; c < NC; c++) tcol[c] += wc[c][p] * cv;
    }
#pragma unroll
    for (int c = 0; c < NC; c++) tmpL[c][t] = tcol[c];
  }
  __syncthreads();

  if (t < NC * NC) {
    int c = t / NC, c2 = t % NC;
    double s = 0.0;
    for (int q = 0; q < NA; q++) s += tmpL[c][q] * wc[c2][q];
    interA[c][c2] = s;
  }
  if (t >= 64 && t < 64 + NC) {
    int c = t - 64;
    double s = 0.0;
    for (int p = 0; p < NA; p++) s += wc[c][p] * (double)r[p];
    interb[c] = s;
  }
  __syncthreads();

  if (t == 0) {
    double A[NC][NC], b[NC];
    for (int a = 0; a < NC; a++) {
      b[a] = interb[a];
      for (int q = 0; q < NC; q++) A[a][q] = interA[a][q];
    }
    // LU with partial pivoting (8x8, serial)
    for (int k = 0; k < NC; k++) {
      int p = k; double mx = fabs(A[k][k]);
      for (int i2 = k + 1; i2 < NC; i2++) {
        double v = fabs(A[i2][k]);
        if (v > mx) { mx = v; p = i2; }
      }
      if (p != k) {
        for (int q = 0; q < NC; q++) { double tv = A[k][q]; A[k][q] = A[p][q]; A[p][q] = tv; }
        double tb = b[k]; b[k] = b[p]; b[p] = tb;
      }
      for (int i2 = k + 1; i2 < NC; i2++) {
        double f = A[i2][k] / A[k][k];
        b[i2] -= f * b[k];
        for (int q = k + 1; q < NC; q++) A[i2][q] -= f * A[k][q];
      }
    }
    double w[NC];
    for (int a = NC - 1; a >= 0; a--) {
      double s = b[a];
      for (int q = a + 1; q < NC; q++) s -= A[a][q] * w[q];
      w[a] = s / A[a][a];
    }
    double ssum = 0.0;
    for (int a = 0; a < NC; a++) ssum += w[a];
    for (int a = 0; a < NC; a++) wi[a] = w[a] / ssum;
  }
  __syncthreads();

  double o = 0.0;
#pragma unroll
  for (int c = 0; c < NC; c++) o += wc[c][t] * wi[c];
  out[(size_t)j * NA + t] = (float)o;
}

extern "C" void kernel_launch(void* const* d_in, const int* in_sizes, int n_in,
                              void* d_out, int out_size, void* d_ws, size_t ws_size,
                              hipStream_t stream) {
  const float* cov  = (const float*)d_in[0];
  const float* rets = (const float*)d_in[1];
  float* out = (float*)d_out;
  char* ws = (char*)d_ws;

  // ws layout (f64 corr is reused as the solve scratch after kmeans)
  const size_t corr_bytes = (size_t)NS * NA * NA * sizeof(double);     // 32 MiB
  double* corr       = (double*)(ws);
  int*    initIdx    = (int*)   (ws + corr_bytes);
  double* inertiaAll = (double*)(ws + corr_bytes + 20480);             // 640*8 int = 20480 B
  int*    ixsAll     = (int*)   (ws + corr_bytes + 20480 + 5120);      // 640 doubles = 5120 B
  double* buf_all    = corr;    // alias: corr dead after kmeans

  hipLaunchKernelGGL(nco_corr_kernel,   dim3(NS * NA), dim3(NA), 0, stream, cov, corr);
  hipLaunchKernelGGL(nco_init_kernel,   dim3(NS * NI), dim3(NA), 0, stream, initIdx);
  hipLaunchKernelGGL(nco_kmeans_kernel, dim3(NS * NI), dim3(NA), 0, stream,
                     corr, initIdx, ixsAll, inertiaAll);
  hipLaunchKernelGGL(nco_solve_kernel,  dim3(NS),      dim3(NA), 0, stream,
                     cov, rets, ixsAll, inertiaAll, buf_all, out);
}